// Round 5
// baseline (3339.539 us; speedup 1.0000x reference)
//
#include <hip/hip_runtime.h>
#include <hip/hip_bf16.h>

// CGCNN: 3x CGConv + projection + mean-pool + 2-layer MLP.
// Round 11:
//  - edge_msg epilogue made branch-free: one ds_add_f32 per message into the
//    LDS accumulator (Round 10's run-length reduce had per-reg branches that
//    diverge across the wave's 4 lq-groups -> both-paths serialization;
//    ~3100 issued VALU/wave vs ~900 useful).
//  - node gates moved to MFMA: hb = bf16-packed h (written by proj2/relu2 for
//    free), Wpk = pre-packed bf16 weight columns; node_gemmM does 64
//    mfma_16x16x32_bf16 per wave, A-tile in LDS with stride-68 padding
//    (breaks the D=128 all-lanes-one-bank trap), B-frags from L2-hot Wpk.
//    Replaces the f32 VALU node_gemm2 (83 us/layer FMA floor).

#define N_NODES 100000
#define N_EDGES 1600000
#define HID 128
#define SCAN_BLOCKS 391  // ceil(100000/256)

typedef unsigned int uint;
typedef short bf16x8 __attribute__((ext_vector_type(8)));
typedef float f32x4 __attribute__((ext_vector_type(4)));

__device__ inline float bflo(uint u) { return __uint_as_float(u << 16); }
__device__ inline float bfhi(uint u) { return __uint_as_float(u & 0xffff0000u); }
__device__ inline uint pack_bf16_2(float a, float b) {
  uint ua = __float_as_uint(a), ub = __float_as_uint(b);
  ua = (ua + 0x7fffu + ((ua >> 16) & 1u)) >> 16;
  ub = (ub + 0x7fffu + ((ub >> 16) & 1u)) >> 16;
  return ua | (ub << 16);
}
__device__ inline float sigmoidf_(float x) {
  return __builtin_amdgcn_rcpf(1.f + __expf(-x));
}
__device__ inline float softplusf_(float x) {
  return fmaxf(x, 0.f) + __logf(1.f + __expf(-fabsf(x)));
}

// ---------------- CSR build ----------------
__global__ __launch_bounds__(256) void hist_k(const int* __restrict__ ei,
                                              int* __restrict__ deg) {
  int e = blockIdx.x * 256 + threadIdx.x;
  if (e >= N_EDGES) return;
  atomicAdd(&deg[ei[N_EDGES + e]], 1);
}

__global__ __launch_bounds__(256) void scan1_k(const int* __restrict__ deg,
                                               int* __restrict__ rowptr,
                                               int* __restrict__ bsums) {
  __shared__ int s[256];
  int i = blockIdx.x * 256 + threadIdx.x;
  int v = (i < N_NODES) ? deg[i] : 0;
  s[threadIdx.x] = v;
  __syncthreads();
  for (int off = 1; off < 256; off <<= 1) {
    int t = (threadIdx.x >= off) ? s[threadIdx.x - off] : 0;
    __syncthreads();
    s[threadIdx.x] += t;
    __syncthreads();
  }
  if (i < N_NODES) rowptr[i] = s[threadIdx.x] - v;  // exclusive
  if (threadIdx.x == 255) bsums[blockIdx.x] = s[255];
}

__global__ __launch_bounds__(512) void scan2_k(int* __restrict__ bsums) {
  __shared__ int s[512];
  int t = threadIdx.x;
  int v = (t < SCAN_BLOCKS) ? bsums[t] : 0;
  s[t] = v;
  __syncthreads();
  for (int off = 1; off < 512; off <<= 1) {
    int x = (t >= off) ? s[t - off] : 0;
    __syncthreads();
    s[t] += x;
    __syncthreads();
  }
  if (t < SCAN_BLOCKS) bsums[t] = s[t] - v;  // exclusive
}

__global__ __launch_bounds__(256) void scan3_k(int* __restrict__ rowptr,
                                               const int* __restrict__ bsums,
                                               int* __restrict__ cur) {
  int i = blockIdx.x * 256 + threadIdx.x;
  if (i < N_NODES) {
    int r = rowptr[i] + bsums[blockIdx.x];
    rowptr[i] = r;
    cur[i] = r;
  }
  if (i == 0) rowptr[N_NODES] = N_EDGES;
}

// csr entry: {src, e, dst, 0}
__global__ __launch_bounds__(256) void scatter_k(const int* __restrict__ ei,
                                                 int* __restrict__ cur,
                                                 uint4* __restrict__ csr) {
  int e = blockIdx.x * 256 + threadIdx.x;
  if (e >= N_EDGES) return;
  int d = ei[N_EDGES + e];
  int pos = atomicAdd(&cur[d], 1);
  csr[pos] = make_uint4((uint)ei[e], (uint)e, (uint)d, 0u);
}

// ---- ea_pack: bf16-pair pack of edge_attr in CSR order (built once) ----
__global__ __launch_bounds__(256) void ea_pack(const float* __restrict__ ea,
                                               const uint4* __restrict__ csr,
                                               uint4* __restrict__ eab) {
  long long t = (long long)blockIdx.x * 256 + threadIdx.x;  // 8 floats/thread
  int p = (int)(t >> 2), q = (int)(t & 3);
  if (p >= N_EDGES) return;
  uint e = csr[p].y;
  const float4* er = (const float4*)(ea + (long long)e * 32 + q * 8);
  float4 a0 = er[0], a1 = er[1];
  uint4 pk;
  pk.x = pack_bf16_2(a0.x, a0.y);
  pk.y = pack_bf16_2(a0.z, a0.w);
  pk.z = pack_bf16_2(a1.x, a1.y);
  pk.w = pack_bf16_2(a1.z, a1.w);
  eab[(long long)p * 4 + q] = pk;
}

// ---------------- conv1 (channels=3) ----------------
__global__ __launch_bounds__(256) void conv1_edge(
    const float* __restrict__ x, const int* __restrict__ ei,
    const float* __restrict__ ea,
    const float* __restrict__ Wf, const float* __restrict__ bf,
    const float* __restrict__ Ws, const float* __restrict__ bs,
    float* __restrict__ agg1) {
  int e = blockIdx.x * 256 + threadIdx.x;
  if (e >= N_EDGES) return;
  int src = ei[e], dst = ei[N_EDGES + e];
  float z[38];
#pragma unroll
  for (int k = 0; k < 3; ++k) z[k] = x[dst * 3 + k];
#pragma unroll
  for (int k = 0; k < 3; ++k) z[3 + k] = x[src * 3 + k];
  const float4* er4 = (const float4*)(ea + (long long)e * 32);
#pragma unroll
  for (int k = 0; k < 8; ++k) {
    float4 v = er4[k];
    z[6 + 4 * k + 0] = v.x;
    z[6 + 4 * k + 1] = v.y;
    z[6 + 4 * k + 2] = v.z;
    z[6 + 4 * k + 3] = v.w;
  }
#pragma unroll
  for (int c = 0; c < 3; ++c) {
    float f = bf[c], s = bs[c];
#pragma unroll
    for (int k = 0; k < 38; ++k) {
      f = fmaf(z[k], Wf[k * 3 + c], f);
      s = fmaf(z[k], Ws[k * 3 + c], s);
    }
    atomicAdd(&agg1[dst * 3 + c], sigmoidf_(f) * softplusf_(s));
  }
}

// -------- projection: h = relu((x+agg1)@Wp+bp); also write bf16-pair hb ----
__global__ __launch_bounds__(256) void proj2(
    const float* __restrict__ x, const float* __restrict__ agg1,
    const float* __restrict__ Wp, const float* __restrict__ bp,
    float* __restrict__ h, uint* __restrict__ hb) {
  long long i = (long long)blockIdx.x * 256 + threadIdx.x;  // node*64 + jp
  if (i >= (long long)N_NODES * 64) return;
  int n = (int)(i >> 6), jp = (int)(i & 63);
  int j0 = jp * 2;
  float v0 = x[n * 3 + 0] + agg1[n * 3 + 0];
  float v1 = x[n * 3 + 1] + agg1[n * 3 + 1];
  float v2 = x[n * 3 + 2] + agg1[n * 3 + 2];
  float a0 = bp[j0], a1 = bp[j0 + 1];
  a0 = fmaf(v0, Wp[0 * HID + j0], a0);
  a0 = fmaf(v1, Wp[1 * HID + j0], a0);
  a0 = fmaf(v2, Wp[2 * HID + j0], a0);
  a1 = fmaf(v0, Wp[0 * HID + j0 + 1], a1);
  a1 = fmaf(v1, Wp[1 * HID + j0 + 1], a1);
  a1 = fmaf(v2, Wp[2 * HID + j0 + 1], a1);
  a0 = fmaxf(a0, 0.f);
  a1 = fmaxf(a1, 0.f);
  *(float2*)&h[(long long)n * HID + j0] = make_float2(a0, a1);
  hb[(long long)n * 64 + jp] = pack_bf16_2(a0, a1);
}

// ---- w_prep2: node weights packed per column as bf16 k-pairs ----
// Wpk[((p*2+m)*128 + c)*64 + kk] = bf16{W[p*128+2kk][c], W[p*128+2kk+1][c]}
// p: 0 dst (W rows 0..127), 1 src (rows 128..255); m: 0 Wf, 1 Ws.
__global__ __launch_bounds__(256) void w_prep2(const float* __restrict__ Wf,
                                               const float* __restrict__ Ws,
                                               uint* __restrict__ Wpk) {
  int row = blockIdx.x * 256 + threadIdx.x;  // 0..511
  int pm = row >> 7;
  int c = row & 127;
  const float* W = (pm & 1) ? Ws : Wf;
  int rowoff = (pm >> 1) * 128;
  for (int kk = 0; kk < 64; ++kk) {
    float a = W[(rowoff + 2 * kk) * 128 + c];
    float b = W[(rowoff + 2 * kk + 1) * 128 + c];
    Wpk[row * 64 + kk] = pack_bf16_2(a, b);
  }
}

// ---- node_gemmM: MFMA node-gate GEMM -> Pb packed {f,s} bf16 pairs ----
// grid (2 parts, 1563 m-tiles); block 256 = 4 waves; wave owns 16 rows.
// Pb[node][256]: [0..127]={f_dst+bf, s_dst+bs} per ch; [128..255]={f_src,s_src}
#define NG_STR 68  // LDS row stride (dwords): 272B, 16B-aligned, 2-way banks
__global__ __launch_bounds__(256, 4) void node_gemmM(
    const uint* __restrict__ hb, const uint* __restrict__ Wpk,
    const float* __restrict__ bf, const float* __restrict__ bs,
    uint* __restrict__ Pb) {
  __shared__ uint Alds[64 * NG_STR];
  int part = blockIdx.x;
  int m0 = blockIdx.y * 64;
  int tid = threadIdx.x;
  // stage A: 64 rows x 64 dwords (bf16 k-pairs), 4 threads/row x 16 dwords
  {
    int r = tid >> 2, q = tid & 3;
    int row = m0 + r;
    uint* d = &Alds[r * NG_STR + q * 16];
    if (row < N_NODES) {
      const uint4* s4 = (const uint4*)&hb[(long long)row * 64 + q * 16];
      uint4 v0 = s4[0], v1 = s4[1], v2 = s4[2], v3 = s4[3];
      *(uint4*)(d + 0) = v0; *(uint4*)(d + 4) = v1;
      *(uint4*)(d + 8) = v2; *(uint4*)(d + 12) = v3;
    } else {
      uint4 z = make_uint4(0, 0, 0, 0);
      *(uint4*)(d + 0) = z; *(uint4*)(d + 4) = z;
      *(uint4*)(d + 8) = z; *(uint4*)(d + 12) = z;
    }
  }
  __syncthreads();
  int wave = tid >> 6, lane = tid & 63;
  int l15 = lane & 15, lq = lane >> 4;
  int arow = wave * 16 + l15;
  const uint* WpF = Wpk + (part * 2 + 0) * 128 * 64;
  const uint* WpS = Wpk + (part * 2 + 1) * 128 * 64;
  f32x4 accF[8], accS[8];
#pragma unroll
  for (int nt = 0; nt < 8; ++nt) {
    f32x4 z = {0.f, 0.f, 0.f, 0.f};
    accF[nt] = z;
    accS[nt] = z;
  }
#pragma unroll
  for (int ks = 0; ks < 4; ++ks) {
    bf16x8 afr = *(const bf16x8*)&Alds[arow * NG_STR + ks * 16 + lq * 4];
#pragma unroll
    for (int nt = 0; nt < 8; ++nt) {
      bf16x8 bF = *(const bf16x8*)&WpF[(nt * 16 + l15) * 64 + ks * 16 + lq * 4];
      bf16x8 bS = *(const bf16x8*)&WpS[(nt * 16 + l15) * 64 + ks * 16 + lq * 4];
      accF[nt] = __builtin_amdgcn_mfma_f32_16x16x32_bf16(afr, bF, accF[nt], 0, 0, 0);
      accS[nt] = __builtin_amdgcn_mfma_f32_16x16x32_bf16(afr, bS, accS[nt], 0, 0, 0);
    }
  }
  // epilogue: C col=lane&15 -> channel nt*16+l15; row=lq*4+reg -> node
#pragma unroll
  for (int nt = 0; nt < 8; ++nt) {
    int c = nt * 16 + l15;
    float fb = (part == 0) ? bf[c] : 0.f;
    float sb = (part == 0) ? bs[c] : 0.f;
#pragma unroll
    for (int reg = 0; reg < 4; ++reg) {
      int node = m0 + wave * 16 + lq * 4 + reg;
      if (node < N_NODES) {
        Pb[(long long)node * 256 + part * 128 + c] =
            pack_bf16_2(accF[nt][reg] + fb, accS[nt][reg] + sb);
      }
    }
  }
}

// ---- w_prep: Btg[ch 0..255][16 dwords] = bf16{W[256+2k][c], W[256+2k+1][c]} ----
__global__ __launch_bounds__(256) void w_prep(const float* __restrict__ Wf,
                                              const float* __restrict__ Ws,
                                              uint* __restrict__ Btg) {
  int t = threadIdx.x;
  const float* W = (t < 128) ? Wf : Ws;
  int c = t & 127;
#pragma unroll
  for (int kk = 0; kk < 16; ++kk) {
    float a = W[(256 + 2 * kk) * 128 + c];
    float b = W[(256 + 2 * kk + 1) * 128 + c];
    Btg[t * 16 + kk] = pack_bf16_2(a, b);
  }
}

// ---- edge_msg: MFMA edge-gemm + gates + activations + LDS-accumulated
//      aggregation (branch-free ds_add per message); complete nodes flushed
//      with plain RMW + relu, straddlers with global atomics ----
#define EMSG_EB 64
#define LSTR 20  // LDS row stride in dwords (80B): b128-aligned, conflict-lite
#define CAP 16   // max tracked distinct dsts per window (typ ~5)
__global__ __launch_bounds__(256, 4) void edge_msg(
    const uint* __restrict__ Pb, const uint4* __restrict__ eab,
    const uint* __restrict__ Btg, const uint4* __restrict__ csr,
    const int* __restrict__ rowptr, float* __restrict__ h) {
  __shared__ uint Alds[EMSG_EB * LSTR];
  __shared__ uint Blds[256 * LSTR];
  __shared__ float accL[CAP * 128];
  __shared__ int dstL[64], srcL[64], liL[64];
  __shared__ int dlist[CAP], compL[CAP];
  __shared__ int nDistS;
  int tid = threadIdx.x;
  int j0 = blockIdx.x * EMSG_EB;
  // stage A: CSR-ordered pre-packed edge rows, straight 4KB copy
  {
    int r = tid >> 2, q = tid & 3;
    uint4 v = eab[(long long)j0 * 4 + tid];
    *(uint4*)&Alds[r * LSTR + q * 4] = v;
  }
  // stage B: weights
  {
    const uint4* s4 = (const uint4*)(Btg + tid * 16);
    uint4 v0 = s4[0], v1 = s4[1], v2 = s4[2], v3 = s4[3];
    uint* d = &Blds[tid * LSTR];
    *(uint4*)(d + 0) = v0; *(uint4*)(d + 4) = v1;
    *(uint4*)(d + 8) = v2; *(uint4*)(d + 12) = v3;
  }
  // zero the accumulator (2048 dwords)
#pragma unroll
  for (int i = 0; i < (CAP * 128) / 256; ++i) accL[tid + i * 256] = 0.f;
  // wave 0: dst/src lists, local-dst index, completeness
  if (tid < 64) {
    uint4 cj = csr[j0 + tid];
    int d = (int)cj.z;
    dstL[tid] = d;
    srcL[tid] = (int)cj.x;
    int dprev = __shfl_up(d, 1, 64);
    bool flag = (tid == 0) || (d != dprev);
    unsigned long long m = __ballot(flag);
    unsigned long long pre = (tid == 63) ? ~0ull : ((1ull << (tid + 1)) - 1);
    int li = __popcll(m & pre) - 1;
    liL[tid] = li;
    if (flag && li < CAP) {
      dlist[li] = d;
      int r0 = rowptr[d], r1 = rowptr[d + 1];
      compL[li] = ((r0 == j0 + tid) && (r1 <= j0 + EMSG_EB)) ? 1 : 0;
    }
    if (tid == 0) nDistS = __popcll(m);
  }
  __syncthreads();
  int wave = tid >> 6, lane = tid & 63;
  int c0w = wave * 32;  // 32 channels per wave
  int l15 = lane & 15, lq = lane >> 4;
  bf16x8 afr[4], bfr[4];
#pragma unroll
  for (int mt = 0; mt < 4; ++mt)
    afr[mt] = *(const bf16x8*)&Alds[(mt * 16 + l15) * LSTR + lq * 4];
  int chs0 = c0w + l15, chs1 = c0w + 16 + l15;
  bfr[0] = *(const bf16x8*)&Blds[chs0 * LSTR + lq * 4];
  bfr[1] = *(const bf16x8*)&Blds[chs1 * LSTR + lq * 4];
  bfr[2] = *(const bf16x8*)&Blds[(128 + chs0) * LSTR + lq * 4];
  bfr[3] = *(const bf16x8*)&Blds[(128 + chs1) * LSTR + lq * 4];
  f32x4 acc[4][4];
#pragma unroll
  for (int mt = 0; mt < 4; ++mt)
#pragma unroll
    for (int nt = 0; nt < 4; ++nt) {
      f32x4 z = {0.f, 0.f, 0.f, 0.f};
      acc[mt][nt] = __builtin_amdgcn_mfma_f32_16x16x32_bf16(afr[mt], bfr[nt], z, 0, 0, 0);
    }
  // branch-free epilogue: one ds_add per message (li<CAP), global otherwise
#pragma unroll
  for (int mt = 0; mt < 4; ++mt) {
    int o = mt * 16 + lq * 4;
    int dsts[4], srcs[4], lis[4];
#pragma unroll
    for (int reg = 0; reg < 4; ++reg) {
      dsts[reg] = dstL[o + reg];
      srcs[reg] = srcL[o + reg];
      lis[reg] = liL[o + reg];
    }
#pragma unroll
    for (int cp = 0; cp < 2; ++cp) {
      int c = (cp ? chs1 : chs0);
#pragma unroll
      for (int reg = 0; reg < 4; ++reg) {
        uint gd = Pb[(long long)dsts[reg] * 256 + c];
        uint gs = Pb[(long long)srcs[reg] * 256 + 128 + c];
        float f = acc[mt][cp][reg] + bflo(gd) + bflo(gs);
        float s = acc[mt][2 + cp][reg] + bfhi(gd) + bfhi(gs);
        float mr = sigmoidf_(f) * softplusf_(s);
        if (lis[reg] < CAP) {
          atomicAdd(&accL[lis[reg] * 128 + c], mr);
        } else {
          atomicAdd(&h[(long long)dsts[reg] * HID + c], mr);
        }
      }
    }
  }
  __syncthreads();
  // flush: complete nodes -> plain RMW + relu; straddlers -> global atomic
  int nD = nDistS;
  if (nD > CAP) nD = CAP;
  int c = tid & 127;
  for (int li = tid >> 7; li < nD; li += 2) {
    int d = dlist[li];
    float v = accL[li * 128 + c];
    float* hp = &h[(long long)d * HID + c];
    if (compL[li]) {
      *hp = fmaxf(*hp + v, 0.f);
    } else {
      atomicAdd(hp, v);
    }
  }
}

// ---- relu2: relu h in place + write bf16-pair hb (for next node_gemmM) ----
__global__ __launch_bounds__(256) void relu2(float* __restrict__ h,
                                             uint* __restrict__ hb) {
  const int total = N_NODES * 32;  // float4 granularity
  for (int i = blockIdx.x * 256 + threadIdx.x; i < total; i += gridDim.x * 256) {
    float4 v = ((float4*)h)[i];
    v.x = fmaxf(v.x, 0.f); v.y = fmaxf(v.y, 0.f);
    v.z = fmaxf(v.z, 0.f); v.w = fmaxf(v.w, 0.f);
    ((float4*)h)[i] = v;
    uint2 o;
    o.x = pack_bf16_2(v.x, v.y);
    o.y = pack_bf16_2(v.z, v.w);
    *(uint2*)&hb[(long long)i * 2] = o;
  }
}

// ---- relu in place over h (final layer; no hb needed) ----
__global__ __launch_bounds__(256) void relu_k(float* __restrict__ h) {
  const int total = N_NODES * HID / 4;
  for (int i = blockIdx.x * 256 + threadIdx.x; i < total; i += gridDim.x * 256) {
    float4 v = ((float4*)h)[i];
    v.x = fmaxf(v.x, 0.f); v.y = fmaxf(v.y, 0.f);
    v.z = fmaxf(v.z, 0.f); v.w = fmaxf(v.w, 0.f);
    ((float4*)h)[i] = v;
  }
}

// -------- segmented mean pool (batch sorted) --------
#define POOL_NODES 128
__global__ __launch_bounds__(128) void pool2(
    const float* __restrict__ h, const int* __restrict__ batch,
    float* __restrict__ sums, float* __restrict__ cnts) {
  int n0 = blockIdx.x * POOL_NODES;
  if (n0 >= N_NODES) return;
  int t = threadIdx.x;
  int nEnd = n0 + POOL_NODES;
  if (nEnd > N_NODES) nEnd = N_NODES;
  float acc = 0.f;
  int bcur = batch[n0];
  int cnt = 0;
  for (int n = n0; n < nEnd; ++n) {
    int b = batch[n];
    if (b != bcur) {
      atomicAdd(&sums[bcur * HID + t], acc);
      if (t == 0) atomicAdd(&cnts[bcur], (float)cnt);
      acc = 0.f; cnt = 0; bcur = b;
    }
    acc += h[(long long)n * HID + t];
    ++cnt;
  }
  atomicAdd(&sums[bcur * HID + t], acc);
  if (t == 0) atomicAdd(&cnts[bcur], (float)cnt);
}

// ---------------- graph MLP ----------------
__global__ __launch_bounds__(128) void mlpA(
    const float* __restrict__ sums, const float* __restrict__ cnts,
    const float* __restrict__ W1, const float* __restrict__ b1,
    float* __restrict__ g) {
  __shared__ float pl[HID];
  int gr = blockIdx.x, j = threadIdx.x;
  float cnt = fmaxf(cnts[gr], 1.f);
  pl[j] = sums[gr * HID + j] / cnt;
  __syncthreads();
  float acc = b1[j];
#pragma unroll 8
  for (int k = 0; k < HID; ++k) acc = fmaf(pl[k], W1[k * HID + j], acc);
  g[gr * HID + j] = fmaxf(acc, 0.f);
}

__global__ __launch_bounds__(256) void mlpB(
    const float* __restrict__ g, const float* __restrict__ W2,
    const float* __restrict__ b2, float* __restrict__ out) {
  int t = threadIdx.x;
  if (t >= 64 * 3) return;
  int gr = t / 3, o = t % 3;
  float acc = b2[o];
#pragma unroll 8
  for (int k = 0; k < HID; ++k) acc = fmaf(g[gr * HID + k], W2[k * 3 + o], acc);
  out[t] = acc;
}

extern "C" void kernel_launch(void* const* d_in, const int* in_sizes, int n_in,
                              void* d_out, int out_size, void* d_ws, size_t ws_size,
                              hipStream_t stream) {
  const float* x   = (const float*)d_in[0];
  const int*   ei  = (const int*)d_in[1];
  const float* ea  = (const float*)d_in[2];
  const int*   bat = (const int*)d_in[3];
  const float* Wf1 = (const float*)d_in[4];
  const float* bf1 = (const float*)d_in[5];
  const float* Ws1 = (const float*)d_in[6];
  const float* bs1 = (const float*)d_in[7];
  const float* Wp  = (const float*)d_in[8];
  const float* bp  = (const float*)d_in[9];
  const float* Wf2 = (const float*)d_in[10];
  const float* bf2 = (const float*)d_in[11];
  const float* Ws2 = (const float*)d_in[12];
  const float* bs2 = (const float*)d_in[13];
  const float* Wf3 = (const float*)d_in[14];
  const float* bf3 = (const float*)d_in[15];
  const float* Ws3 = (const float*)d_in[16];
  const float* bs3 = (const float*)d_in[17];
  const float* W1  = (const float*)d_in[18];
  const float* b1  = (const float*)d_in[19];
  const float* W2  = (const float*)d_in[20];
  const float* b2  = (const float*)d_in[21];
  float* out = (float*)d_out;

  char* w = (char*)d_ws;
  size_t off = 0;
  auto alloc = [&](size_t bytes) {
    void* p = w + off;
    off += (bytes + 255) & ~(size_t)255;
    return p;
  };
  int*   deg    = (int*)alloc((size_t)N_NODES * 4);
  int*   rowptr = (int*)alloc((size_t)(N_NODES + 1) * 4);
  int*   cur    = (int*)alloc((size_t)N_NODES * 4);
  int*   bsums  = (int*)alloc((size_t)512 * 4);
  uint4* csr    = (uint4*)alloc((size_t)N_EDGES * 16);       // 25.6 MB
  float* agg1   = (float*)alloc((size_t)N_NODES * 3 * 4);    // 1.2 MB
  float* h      = (float*)alloc((size_t)N_NODES * HID * 4);  // 51.2 MB
  uint*  hb     = (uint*)alloc((size_t)N_NODES * 64 * 4);    // 25.6 MB
  uint*  Pb     = (uint*)alloc((size_t)N_NODES * 256 * 4);   // 102.4 MB
  uint4* eab    = (uint4*)alloc((size_t)N_EDGES * 64);       // 102.4 MB
  float* sums   = (float*)alloc((size_t)64 * HID * 4);
  float* cnts   = (float*)alloc((size_t)64 * 4);
  float* g      = (float*)alloc((size_t)64 * HID * 4);
  uint*  Btg    = (uint*)alloc((size_t)256 * 16 * 4);        // 16 KB
  uint*  Wpk    = (uint*)alloc((size_t)512 * 64 * 4);        // 128 KB
  (void)ws_size;  // total ~310 MB

  // ---- CSR build ----
  hipMemsetAsync(deg, 0, (size_t)N_NODES * 4, stream);
  hist_k<<<(N_EDGES + 255) / 256, 256, 0, stream>>>(ei, deg);
  scan1_k<<<SCAN_BLOCKS, 256, 0, stream>>>(deg, rowptr, bsums);
  scan2_k<<<1, 512, 0, stream>>>(bsums);
  scan3_k<<<SCAN_BLOCKS, 256, 0, stream>>>(rowptr, bsums, cur);
  scatter_k<<<(N_EDGES + 255) / 256, 256, 0, stream>>>(ei, cur, csr);
  ea_pack<<<(N_EDGES * 4 + 255) / 256, 256, 0, stream>>>(ea, csr, eab);

  // ---- conv1 ----
  hipMemsetAsync(agg1, 0, (size_t)N_NODES * 3 * 4, stream);
  conv1_edge<<<(N_EDGES + 255) / 256, 256, 0, stream>>>(x, ei, ea, Wf1, bf1, Ws1, bs1, agg1);
  proj2<<<(N_NODES * 64 + 255) / 256, 256, 0, stream>>>(x, agg1, Wp, bp, h, hb);

  dim3 nggrid(2, (N_NODES + 63) / 64);
  int eblocks = N_EDGES / EMSG_EB;  // 25000, exact

  // ---- conv2 ----
  w_prep2<<<2, 256, 0, stream>>>(Wf2, Ws2, Wpk);
  node_gemmM<<<nggrid, 256, 0, stream>>>(hb, Wpk, bf2, bs2, Pb);
  w_prep<<<1, 256, 0, stream>>>(Wf2, Ws2, Btg);
  edge_msg<<<eblocks, 256, 0, stream>>>(Pb, eab, Btg, csr, rowptr, h);
  relu2<<<4096, 256, 0, stream>>>(h, hb);

  // ---- conv3 ----
  w_prep2<<<2, 256, 0, stream>>>(Wf3, Ws3, Wpk);
  node_gemmM<<<nggrid, 256, 0, stream>>>(hb, Wpk, bf3, bs3, Pb);
  w_prep<<<1, 256, 0, stream>>>(Wf3, Ws3, Btg);
  edge_msg<<<eblocks, 256, 0, stream>>>(Pb, eab, Btg, csr, rowptr, h);
  relu_k<<<4096, 256, 0, stream>>>(h);

  // ---- pool + MLP ----
  hipMemsetAsync(sums, 0, (size_t)(64 * HID + 64) * 4, stream);
  pool2<<<(N_NODES + POOL_NODES - 1) / POOL_NODES, POOL_NODES, 0, stream>>>(h, bat, sums, cnts);
  mlpA<<<64, 128, 0, stream>>>(sums, cnts, W1, b1, g);
  mlpB<<<1, 256, 0, stream>>>(g, W2, b2, out);
}

// Round 6
// 1871.034 us; speedup vs baseline: 1.7849x; 1.7849x over previous
//
#include <hip/hip_runtime.h>
#include <hip/hip_bf16.h>

// CGCNN: 3x CGConv + projection + mean-pool + 2-layer MLP.
// Round 12:
//  - REVERT Round 11's branch-free ds_add epilogue (8192 LDS atomics/block
//    serialized the LDS pipe: 205M ds_add/dispatch, VALUBusy 61->21%,
//    2.6x regression). Back to run-length reduce (~2.4K LDS atomics/block).
//  - edge_msg de-LDS'd: A-fragments are wave-invariant (all 4 waves load
//    identical 16B chunks -> L1-absorbed), B-fragments come from the 16KB
//    L2-hot Btg table. Dropping Alds/Blds (25.6KB) + per-mt accumulator
//    scoping cuts regs ~116->~75 and LDS to ~9.3KB; __launch_bounds__(256,6)
//    -> 6 waves/SIMD (+50% latency hiding for the scattered src-gate loads,
//    which bound R10's 425us at 44% occupancy / 17% HBM).
//  - node gates stay on MFMA (node_gemmM + proj2/relu2 bf16 path).

#define N_NODES 100000
#define N_EDGES 1600000
#define HID 128
#define SCAN_BLOCKS 391  // ceil(100000/256)

typedef unsigned int uint;
typedef short bf16x8 __attribute__((ext_vector_type(8)));
typedef float f32x4 __attribute__((ext_vector_type(4)));

__device__ inline float bflo(uint u) { return __uint_as_float(u << 16); }
__device__ inline float bfhi(uint u) { return __uint_as_float(u & 0xffff0000u); }
__device__ inline uint pack_bf16_2(float a, float b) {
  uint ua = __float_as_uint(a), ub = __float_as_uint(b);
  ua = (ua + 0x7fffu + ((ua >> 16) & 1u)) >> 16;
  ub = (ub + 0x7fffu + ((ub >> 16) & 1u)) >> 16;
  return ua | (ub << 16);
}
__device__ inline float sigmoidf_(float x) {
  return __builtin_amdgcn_rcpf(1.f + __expf(-x));
}
__device__ inline float softplusf_(float x) {
  return fmaxf(x, 0.f) + __logf(1.f + __expf(-fabsf(x)));
}

// ---------------- CSR build ----------------
__global__ __launch_bounds__(256) void hist_k(const int* __restrict__ ei,
                                              int* __restrict__ deg) {
  int e = blockIdx.x * 256 + threadIdx.x;
  if (e >= N_EDGES) return;
  atomicAdd(&deg[ei[N_EDGES + e]], 1);
}

__global__ __launch_bounds__(256) void scan1_k(const int* __restrict__ deg,
                                               int* __restrict__ rowptr,
                                               int* __restrict__ bsums) {
  __shared__ int s[256];
  int i = blockIdx.x * 256 + threadIdx.x;
  int v = (i < N_NODES) ? deg[i] : 0;
  s[threadIdx.x] = v;
  __syncthreads();
  for (int off = 1; off < 256; off <<= 1) {
    int t = (threadIdx.x >= off) ? s[threadIdx.x - off] : 0;
    __syncthreads();
    s[threadIdx.x] += t;
    __syncthreads();
  }
  if (i < N_NODES) rowptr[i] = s[threadIdx.x] - v;  // exclusive
  if (threadIdx.x == 255) bsums[blockIdx.x] = s[255];
}

__global__ __launch_bounds__(512) void scan2_k(int* __restrict__ bsums) {
  __shared__ int s[512];
  int t = threadIdx.x;
  int v = (t < SCAN_BLOCKS) ? bsums[t] : 0;
  s[t] = v;
  __syncthreads();
  for (int off = 1; off < 512; off <<= 1) {
    int x = (t >= off) ? s[t - off] : 0;
    __syncthreads();
    s[t] += x;
    __syncthreads();
  }
  if (t < SCAN_BLOCKS) bsums[t] = s[t] - v;  // exclusive
}

__global__ __launch_bounds__(256) void scan3_k(int* __restrict__ rowptr,
                                               const int* __restrict__ bsums,
                                               int* __restrict__ cur) {
  int i = blockIdx.x * 256 + threadIdx.x;
  if (i < N_NODES) {
    int r = rowptr[i] + bsums[blockIdx.x];
    rowptr[i] = r;
    cur[i] = r;
  }
  if (i == 0) rowptr[N_NODES] = N_EDGES;
}

// csr entry: {src, e, dst, 0}
__global__ __launch_bounds__(256) void scatter_k(const int* __restrict__ ei,
                                                 int* __restrict__ cur,
                                                 uint4* __restrict__ csr) {
  int e = blockIdx.x * 256 + threadIdx.x;
  if (e >= N_EDGES) return;
  int d = ei[N_EDGES + e];
  int pos = atomicAdd(&cur[d], 1);
  csr[pos] = make_uint4((uint)ei[e], (uint)e, (uint)d, 0u);
}

// ---- ea_pack: bf16-pair pack of edge_attr in CSR order (built once) ----
__global__ __launch_bounds__(256) void ea_pack(const float* __restrict__ ea,
                                               const uint4* __restrict__ csr,
                                               uint4* __restrict__ eab) {
  long long t = (long long)blockIdx.x * 256 + threadIdx.x;  // 8 floats/thread
  int p = (int)(t >> 2), q = (int)(t & 3);
  if (p >= N_EDGES) return;
  uint e = csr[p].y;
  const float4* er = (const float4*)(ea + (long long)e * 32 + q * 8);
  float4 a0 = er[0], a1 = er[1];
  uint4 pk;
  pk.x = pack_bf16_2(a0.x, a0.y);
  pk.y = pack_bf16_2(a0.z, a0.w);
  pk.z = pack_bf16_2(a1.x, a1.y);
  pk.w = pack_bf16_2(a1.z, a1.w);
  eab[(long long)p * 4 + q] = pk;
}

// ---------------- conv1 (channels=3) ----------------
__global__ __launch_bounds__(256) void conv1_edge(
    const float* __restrict__ x, const int* __restrict__ ei,
    const float* __restrict__ ea,
    const float* __restrict__ Wf, const float* __restrict__ bf,
    const float* __restrict__ Ws, const float* __restrict__ bs,
    float* __restrict__ agg1) {
  int e = blockIdx.x * 256 + threadIdx.x;
  if (e >= N_EDGES) return;
  int src = ei[e], dst = ei[N_EDGES + e];
  float z[38];
#pragma unroll
  for (int k = 0; k < 3; ++k) z[k] = x[dst * 3 + k];
#pragma unroll
  for (int k = 0; k < 3; ++k) z[3 + k] = x[src * 3 + k];
  const float4* er4 = (const float4*)(ea + (long long)e * 32);
#pragma unroll
  for (int k = 0; k < 8; ++k) {
    float4 v = er4[k];
    z[6 + 4 * k + 0] = v.x;
    z[6 + 4 * k + 1] = v.y;
    z[6 + 4 * k + 2] = v.z;
    z[6 + 4 * k + 3] = v.w;
  }
#pragma unroll
  for (int c = 0; c < 3; ++c) {
    float f = bf[c], s = bs[c];
#pragma unroll
    for (int k = 0; k < 38; ++k) {
      f = fmaf(z[k], Wf[k * 3 + c], f);
      s = fmaf(z[k], Ws[k * 3 + c], s);
    }
    atomicAdd(&agg1[dst * 3 + c], sigmoidf_(f) * softplusf_(s));
  }
}

// -------- projection: h = relu((x+agg1)@Wp+bp); also write bf16-pair hb ----
__global__ __launch_bounds__(256) void proj2(
    const float* __restrict__ x, const float* __restrict__ agg1,
    const float* __restrict__ Wp, const float* __restrict__ bp,
    float* __restrict__ h, uint* __restrict__ hb) {
  long long i = (long long)blockIdx.x * 256 + threadIdx.x;  // node*64 + jp
  if (i >= (long long)N_NODES * 64) return;
  int n = (int)(i >> 6), jp = (int)(i & 63);
  int j0 = jp * 2;
  float v0 = x[n * 3 + 0] + agg1[n * 3 + 0];
  float v1 = x[n * 3 + 1] + agg1[n * 3 + 1];
  float v2 = x[n * 3 + 2] + agg1[n * 3 + 2];
  float a0 = bp[j0], a1 = bp[j0 + 1];
  a0 = fmaf(v0, Wp[0 * HID + j0], a0);
  a0 = fmaf(v1, Wp[1 * HID + j0], a0);
  a0 = fmaf(v2, Wp[2 * HID + j0], a0);
  a1 = fmaf(v0, Wp[0 * HID + j0 + 1], a1);
  a1 = fmaf(v1, Wp[1 * HID + j0 + 1], a1);
  a1 = fmaf(v2, Wp[2 * HID + j0 + 1], a1);
  a0 = fmaxf(a0, 0.f);
  a1 = fmaxf(a1, 0.f);
  *(float2*)&h[(long long)n * HID + j0] = make_float2(a0, a1);
  hb[(long long)n * 64 + jp] = pack_bf16_2(a0, a1);
}

// ---- w_prep2: node weights packed per column as bf16 k-pairs ----
// Wpk[((p*2+m)*128 + c)*64 + kk] = bf16{W[p*128+2kk][c], W[p*128+2kk+1][c]}
// p: 0 dst (W rows 0..127), 1 src (rows 128..255); m: 0 Wf, 1 Ws.
__global__ __launch_bounds__(256) void w_prep2(const float* __restrict__ Wf,
                                               const float* __restrict__ Ws,
                                               uint* __restrict__ Wpk) {
  int row = blockIdx.x * 256 + threadIdx.x;  // 0..511
  int pm = row >> 7;
  int c = row & 127;
  const float* W = (pm & 1) ? Ws : Wf;
  int rowoff = (pm >> 1) * 128;
  for (int kk = 0; kk < 64; ++kk) {
    float a = W[(rowoff + 2 * kk) * 128 + c];
    float b = W[(rowoff + 2 * kk + 1) * 128 + c];
    Wpk[row * 64 + kk] = pack_bf16_2(a, b);
  }
}

// ---- node_gemmM: MFMA node-gate GEMM -> Pb packed {f,s} bf16 pairs ----
// grid (2 parts, 1563 m-tiles); block 256 = 4 waves; wave owns 16 rows.
// Pb[node][256]: [0..127]={f_dst+bf, s_dst+bs} per ch; [128..255]={f_src,s_src}
#define NG_STR 68  // LDS row stride (dwords): 272B, 16B-aligned, 2-way banks
__global__ __launch_bounds__(256, 4) void node_gemmM(
    const uint* __restrict__ hb, const uint* __restrict__ Wpk,
    const float* __restrict__ bf, const float* __restrict__ bs,
    uint* __restrict__ Pb) {
  __shared__ uint Alds[64 * NG_STR];
  int part = blockIdx.x;
  int m0 = blockIdx.y * 64;
  int tid = threadIdx.x;
  // stage A: 64 rows x 64 dwords (bf16 k-pairs), 4 threads/row x 16 dwords
  {
    int r = tid >> 2, q = tid & 3;
    int row = m0 + r;
    uint* d = &Alds[r * NG_STR + q * 16];
    if (row < N_NODES) {
      const uint4* s4 = (const uint4*)&hb[(long long)row * 64 + q * 16];
      uint4 v0 = s4[0], v1 = s4[1], v2 = s4[2], v3 = s4[3];
      *(uint4*)(d + 0) = v0; *(uint4*)(d + 4) = v1;
      *(uint4*)(d + 8) = v2; *(uint4*)(d + 12) = v3;
    } else {
      uint4 z = make_uint4(0, 0, 0, 0);
      *(uint4*)(d + 0) = z; *(uint4*)(d + 4) = z;
      *(uint4*)(d + 8) = z; *(uint4*)(d + 12) = z;
    }
  }
  __syncthreads();
  int wave = tid >> 6, lane = tid & 63;
  int l15 = lane & 15, lq = lane >> 4;
  int arow = wave * 16 + l15;
  const uint* WpF = Wpk + (part * 2 + 0) * 128 * 64;
  const uint* WpS = Wpk + (part * 2 + 1) * 128 * 64;
  f32x4 accF[8], accS[8];
#pragma unroll
  for (int nt = 0; nt < 8; ++nt) {
    f32x4 z = {0.f, 0.f, 0.f, 0.f};
    accF[nt] = z;
    accS[nt] = z;
  }
#pragma unroll
  for (int ks = 0; ks < 4; ++ks) {
    bf16x8 afr = *(const bf16x8*)&Alds[arow * NG_STR + ks * 16 + lq * 4];
#pragma unroll
    for (int nt = 0; nt < 8; ++nt) {
      bf16x8 bF = *(const bf16x8*)&WpF[(nt * 16 + l15) * 64 + ks * 16 + lq * 4];
      bf16x8 bS = *(const bf16x8*)&WpS[(nt * 16 + l15) * 64 + ks * 16 + lq * 4];
      accF[nt] = __builtin_amdgcn_mfma_f32_16x16x32_bf16(afr, bF, accF[nt], 0, 0, 0);
      accS[nt] = __builtin_amdgcn_mfma_f32_16x16x32_bf16(afr, bS, accS[nt], 0, 0, 0);
    }
  }
  // epilogue: C col=lane&15 -> channel nt*16+l15; row=lq*4+reg -> node
#pragma unroll
  for (int nt = 0; nt < 8; ++nt) {
    int c = nt * 16 + l15;
    float fb = (part == 0) ? bf[c] : 0.f;
    float sb = (part == 0) ? bs[c] : 0.f;
#pragma unroll
    for (int reg = 0; reg < 4; ++reg) {
      int node = m0 + wave * 16 + lq * 4 + reg;
      if (node < N_NODES) {
        Pb[(long long)node * 256 + part * 128 + c] =
            pack_bf16_2(accF[nt][reg] + fb, accS[nt][reg] + sb);
      }
    }
  }
}

// ---- w_prep: Btg[ch 0..255][16 dwords] = bf16{W[256+2k][c], W[256+2k+1][c]} ----
__global__ __launch_bounds__(256) void w_prep(const float* __restrict__ Wf,
                                              const float* __restrict__ Ws,
                                              uint* __restrict__ Btg) {
  int t = threadIdx.x;
  const float* W = (t < 128) ? Wf : Ws;
  int c = t & 127;
#pragma unroll
  for (int kk = 0; kk < 16; ++kk) {
    float a = W[(256 + 2 * kk) * 128 + c];
    float b = W[(256 + 2 * kk + 1) * 128 + c];
    Btg[t * 16 + kk] = pack_bf16_2(a, b);
  }
}

// ---- edge_msg v3: MFMA edge-gemm (fragments direct from global; A-frags
// wave-invariant -> L1-shared, B-frags from the 16KB L2-hot Btg table),
// run-length-reduced LDS accumulation, completeness-RMW flush ----
#define EMSG_EB 64
#define CAP 16   // max tracked distinct dsts per window (typ ~5)
__global__ __launch_bounds__(256, 6) void edge_msg(
    const uint* __restrict__ Pb, const uint* __restrict__ eab,
    const uint* __restrict__ Btg, const uint4* __restrict__ csr,
    const int* __restrict__ rowptr, float* __restrict__ h) {
  __shared__ float accL[CAP * 128];   // 8 KB
  __shared__ int dstL[64], srcL[64], liL[64];
  __shared__ int dlist[CAP], compL[CAP];
  __shared__ int nDistS;
  int tid = threadIdx.x;
  int j0 = blockIdx.x * EMSG_EB;
  // zero the accumulator (2048 dwords)
#pragma unroll
  for (int i = 0; i < (CAP * 128) / 256; ++i) accL[tid + i * 256] = 0.f;
  // wave 0: dst/src lists, local-dst index, completeness
  if (tid < 64) {
    uint4 cj = csr[j0 + tid];
    int d = (int)cj.z;
    dstL[tid] = d;
    srcL[tid] = (int)cj.x;
    int dprev = __shfl_up(d, 1, 64);
    bool flag = (tid == 0) || (d != dprev);
    unsigned long long m = __ballot(flag);
    unsigned long long pre = (tid == 63) ? ~0ull : ((1ull << (tid + 1)) - 1);
    int li = __popcll(m & pre) - 1;
    liL[tid] = li;
    if (flag && li < CAP) {
      dlist[li] = d;
      int r0 = rowptr[d], r1 = rowptr[d + 1];
      compL[li] = ((r0 == j0 + tid) && (r1 <= j0 + EMSG_EB)) ? 1 : 0;
    }
    if (tid == 0) nDistS = __popcll(m);
  }
  __syncthreads();
  int wave = tid >> 6, lane = tid & 63;
  int c0w = wave * 32;  // 32 channels per wave
  int l15 = lane & 15, lq = lane >> 4;
  int chs0 = c0w + l15, chs1 = c0w + 16 + l15;
  // B fragments: direct from Btg (16KB, L1/L2-resident across blocks)
  bf16x8 bfr0 = *(const bf16x8*)&Btg[chs0 * 16 + lq * 4];
  bf16x8 bfr1 = *(const bf16x8*)&Btg[chs1 * 16 + lq * 4];
  bf16x8 bfr2 = *(const bf16x8*)&Btg[(128 + chs0) * 16 + lq * 4];
  bf16x8 bfr3 = *(const bf16x8*)&Btg[(128 + chs1) * 16 + lq * 4];
  // per-mt phases: 1 A-frag + 4 MFMAs + epilogue (keeps acc liveness at 16)
#pragma unroll
  for (int mt = 0; mt < 4; ++mt) {
    bf16x8 afr =
        *(const bf16x8*)&eab[((long long)(j0 + mt * 16 + l15)) * 16 + lq * 4];
    f32x4 z = {0.f, 0.f, 0.f, 0.f};
    f32x4 accf0 = __builtin_amdgcn_mfma_f32_16x16x32_bf16(afr, bfr0, z, 0, 0, 0);
    f32x4 accf1 = __builtin_amdgcn_mfma_f32_16x16x32_bf16(afr, bfr1, z, 0, 0, 0);
    f32x4 accs0 = __builtin_amdgcn_mfma_f32_16x16x32_bf16(afr, bfr2, z, 0, 0, 0);
    f32x4 accs1 = __builtin_amdgcn_mfma_f32_16x16x32_bf16(afr, bfr3, z, 0, 0, 0);
    int o = mt * 16 + lq * 4;
    int dsts[4], srcs[4], lis[4];
#pragma unroll
    for (int reg = 0; reg < 4; ++reg) {
      dsts[reg] = dstL[o + reg];
      srcs[reg] = srcL[o + reg];
      lis[reg] = liL[o + reg];
    }
#pragma unroll
    for (int cp = 0; cp < 2; ++cp) {
      int c = (cp ? chs1 : chs0);
      f32x4 af = cp ? accf1 : accf0;
      f32x4 as = cp ? accs1 : accs0;
      float mr[4];
#pragma unroll
      for (int reg = 0; reg < 4; ++reg) {
        uint gd = Pb[(long long)dsts[reg] * 256 + c];
        uint gs = Pb[(long long)srcs[reg] * 256 + 128 + c];
        float f = af[reg] + bflo(gd) + bflo(gs);
        float s = as[reg] + bfhi(gd) + bfhi(gs);
        mr[reg] = sigmoidf_(f) * softplusf_(s);
      }
      float racc = mr[0];
      int cl = lis[0], cd = dsts[0];
#pragma unroll
      for (int reg = 1; reg < 4; ++reg) {
        if (lis[reg] == cl) {
          racc += mr[reg];
        } else {
          if (cl < CAP) atomicAdd(&accL[cl * 128 + c], racc);
          else atomicAdd(&h[(long long)cd * HID + c], racc);
          cl = lis[reg]; cd = dsts[reg]; racc = mr[reg];
        }
      }
      if (cl < CAP) atomicAdd(&accL[cl * 128 + c], racc);
      else atomicAdd(&h[(long long)cd * HID + c], racc);
    }
  }
  __syncthreads();
  // flush: complete nodes -> plain RMW + relu; straddlers -> global atomic
  int nD = nDistS;
  if (nD > CAP) nD = CAP;
  int c = tid & 127;
  for (int li = tid >> 7; li < nD; li += 2) {
    int d = dlist[li];
    float v = accL[li * 128 + c];
    float* hp = &h[(long long)d * HID + c];
    if (compL[li]) {
      *hp = fmaxf(*hp + v, 0.f);
    } else {
      atomicAdd(hp, v);
    }
  }
}

// ---- relu2: relu h in place + write bf16-pair hb (for next node_gemmM) ----
__global__ __launch_bounds__(256) void relu2(float* __restrict__ h,
                                             uint* __restrict__ hb) {
  const int total = N_NODES * 32;  // float4 granularity
  for (int i = blockIdx.x * 256 + threadIdx.x; i < total; i += gridDim.x * 256) {
    float4 v = ((float4*)h)[i];
    v.x = fmaxf(v.x, 0.f); v.y = fmaxf(v.y, 0.f);
    v.z = fmaxf(v.z, 0.f); v.w = fmaxf(v.w, 0.f);
    ((float4*)h)[i] = v;
    uint2 o;
    o.x = pack_bf16_2(v.x, v.y);
    o.y = pack_bf16_2(v.z, v.w);
    *(uint2*)&hb[(long long)i * 2] = o;
  }
}

// ---- relu in place over h (final layer; no hb needed) ----
__global__ __launch_bounds__(256) void relu_k(float* __restrict__ h) {
  const int total = N_NODES * HID / 4;
  for (int i = blockIdx.x * 256 + threadIdx.x; i < total; i += gridDim.x * 256) {
    float4 v = ((float4*)h)[i];
    v.x = fmaxf(v.x, 0.f); v.y = fmaxf(v.y, 0.f);
    v.z = fmaxf(v.z, 0.f); v.w = fmaxf(v.w, 0.f);
    ((float4*)h)[i] = v;
  }
}

// -------- segmented mean pool (batch sorted) --------
#define POOL_NODES 128
__global__ __launch_bounds__(128) void pool2(
    const float* __restrict__ h, const int* __restrict__ batch,
    float* __restrict__ sums, float* __restrict__ cnts) {
  int n0 = blockIdx.x * POOL_NODES;
  if (n0 >= N_NODES) return;
  int t = threadIdx.x;
  int nEnd = n0 + POOL_NODES;
  if (nEnd > N_NODES) nEnd = N_NODES;
  float acc = 0.f;
  int bcur = batch[n0];
  int cnt = 0;
  for (int n = n0; n < nEnd; ++n) {
    int b = batch[n];
    if (b != bcur) {
      atomicAdd(&sums[bcur * HID + t], acc);
      if (t == 0) atomicAdd(&cnts[bcur], (float)cnt);
      acc = 0.f; cnt = 0; bcur = b;
    }
    acc += h[(long long)n * HID + t];
    ++cnt;
  }
  atomicAdd(&sums[bcur * HID + t], acc);
  if (t == 0) atomicAdd(&cnts[bcur], (float)cnt);
}

// ---------------- graph MLP ----------------
__global__ __launch_bounds__(128) void mlpA(
    const float* __restrict__ sums, const float* __restrict__ cnts,
    const float* __restrict__ W1, const float* __restrict__ b1,
    float* __restrict__ g) {
  __shared__ float pl[HID];
  int gr = blockIdx.x, j = threadIdx.x;
  float cnt = fmaxf(cnts[gr], 1.f);
  pl[j] = sums[gr * HID + j] / cnt;
  __syncthreads();
  float acc = b1[j];
#pragma unroll 8
  for (int k = 0; k < HID; ++k) acc = fmaf(pl[k], W1[k * HID + j], acc);
  g[gr * HID + j] = fmaxf(acc, 0.f);
}

__global__ __launch_bounds__(256) void mlpB(
    const float* __restrict__ g, const float* __restrict__ W2,
    const float* __restrict__ b2, float* __restrict__ out) {
  int t = threadIdx.x;
  if (t >= 64 * 3) return;
  int gr = t / 3, o = t % 3;
  float acc = b2[o];
#pragma unroll 8
  for (int k = 0; k < HID; ++k) acc = fmaf(g[gr * HID + k], W2[k * 3 + o], acc);
  out[t] = acc;
}

extern "C" void kernel_launch(void* const* d_in, const int* in_sizes, int n_in,
                              void* d_out, int out_size, void* d_ws, size_t ws_size,
                              hipStream_t stream) {
  const float* x   = (const float*)d_in[0];
  const int*   ei  = (const int*)d_in[1];
  const float* ea  = (const float*)d_in[2];
  const int*   bat = (const int*)d_in[3];
  const float* Wf1 = (const float*)d_in[4];
  const float* bf1 = (const float*)d_in[5];
  const float* Ws1 = (const float*)d_in[6];
  const float* bs1 = (const float*)d_in[7];
  const float* Wp  = (const float*)d_in[8];
  const float* bp  = (const float*)d_in[9];
  const float* Wf2 = (const float*)d_in[10];
  const float* bf2 = (const float*)d_in[11];
  const float* Ws2 = (const float*)d_in[12];
  const float* bs2 = (const float*)d_in[13];
  const float* Wf3 = (const float*)d_in[14];
  const float* bf3 = (const float*)d_in[15];
  const float* Ws3 = (const float*)d_in[16];
  const float* bs3 = (const float*)d_in[17];
  const float* W1  = (const float*)d_in[18];
  const float* b1  = (const float*)d_in[19];
  const float* W2  = (const float*)d_in[20];
  const float* b2  = (const float*)d_in[21];
  float* out = (float*)d_out;

  char* w = (char*)d_ws;
  size_t off = 0;
  auto alloc = [&](size_t bytes) {
    void* p = w + off;
    off += (bytes + 255) & ~(size_t)255;
    return p;
  };
  int*   deg    = (int*)alloc((size_t)N_NODES * 4);
  int*   rowptr = (int*)alloc((size_t)(N_NODES + 1) * 4);
  int*   cur    = (int*)alloc((size_t)N_NODES * 4);
  int*   bsums  = (int*)alloc((size_t)512 * 4);
  uint4* csr    = (uint4*)alloc((size_t)N_EDGES * 16);       // 25.6 MB
  float* agg1   = (float*)alloc((size_t)N_NODES * 3 * 4);    // 1.2 MB
  float* h      = (float*)alloc((size_t)N_NODES * HID * 4);  // 51.2 MB
  uint*  hb     = (uint*)alloc((size_t)N_NODES * 64 * 4);    // 25.6 MB
  uint*  Pb     = (uint*)alloc((size_t)N_NODES * 256 * 4);   // 102.4 MB
  uint*  eab    = (uint*)alloc((size_t)N_EDGES * 64);        // 102.4 MB
  float* sums   = (float*)alloc((size_t)64 * HID * 4);
  float* cnts   = (float*)alloc((size_t)64 * 4);
  float* g      = (float*)alloc((size_t)64 * HID * 4);
  uint*  Btg    = (uint*)alloc((size_t)256 * 16 * 4);        // 16 KB
  uint*  Wpk    = (uint*)alloc((size_t)512 * 64 * 4);        // 128 KB
  (void)ws_size;  // total ~310 MB

  // ---- CSR build ----
  hipMemsetAsync(deg, 0, (size_t)N_NODES * 4, stream);
  hist_k<<<(N_EDGES + 255) / 256, 256, 0, stream>>>(ei, deg);
  scan1_k<<<SCAN_BLOCKS, 256, 0, stream>>>(deg, rowptr, bsums);
  scan2_k<<<1, 512, 0, stream>>>(bsums);
  scan3_k<<<SCAN_BLOCKS, 256, 0, stream>>>(rowptr, bsums, cur);
  scatter_k<<<(N_EDGES + 255) / 256, 256, 0, stream>>>(ei, cur, csr);
  ea_pack<<<(N_EDGES * 4 + 255) / 256, 256, 0, stream>>>(ea, csr, (uint4*)eab);

  // ---- conv1 ----
  hipMemsetAsync(agg1, 0, (size_t)N_NODES * 3 * 4, stream);
  conv1_edge<<<(N_EDGES + 255) / 256, 256, 0, stream>>>(x, ei, ea, Wf1, bf1, Ws1, bs1, agg1);
  proj2<<<(N_NODES * 64 + 255) / 256, 256, 0, stream>>>(x, agg1, Wp, bp, h, hb);

  dim3 nggrid(2, (N_NODES + 63) / 64);
  int eblocks = N_EDGES / EMSG_EB;  // 25000, exact

  // ---- conv2 ----
  w_prep2<<<2, 256, 0, stream>>>(Wf2, Ws2, Wpk);
  node_gemmM<<<nggrid, 256, 0, stream>>>(hb, Wpk, bf2, bs2, Pb);
  w_prep<<<1, 256, 0, stream>>>(Wf2, Ws2, Btg);
  edge_msg<<<eblocks, 256, 0, stream>>>(Pb, eab, Btg, csr, rowptr, h);
  relu2<<<4096, 256, 0, stream>>>(h, hb);

  // ---- conv3 ----
  w_prep2<<<2, 256, 0, stream>>>(Wf3, Ws3, Wpk);
  node_gemmM<<<nggrid, 256, 0, stream>>>(hb, Wpk, bf3, bs3, Pb);
  w_prep<<<1, 256, 0, stream>>>(Wf3, Ws3, Btg);
  edge_msg<<<eblocks, 256, 0, stream>>>(Pb, eab, Btg, csr, rowptr, h);
  relu_k<<<4096, 256, 0, stream>>>(h);

  // ---- pool + MLP ----
  hipMemsetAsync(sums, 0, (size_t)(64 * HID + 64) * 4, stream);
  pool2<<<(N_NODES + POOL_NODES - 1) / POOL_NODES, POOL_NODES, 0, stream>>>(h, bat, sums, cnts);
  mlpA<<<64, 128, 0, stream>>>(sums, cnts, W1, b1, g);
  mlpB<<<1, 256, 0, stream>>>(g, W2, b2, out);
}